// Round 9
// baseline (430.372 us; speedup 1.0000x reference)
//
#include <hip/hip_runtime.h>
#include <cstdint>
#include <cstddef>

// Problem: B=1, S=2048, H=4096, NH=32, NKV=8, D=128, rope theta 1e4, causal GQA attn.
// Inputs f32: hidden[2048][4096], w_qkv[4096][6144], w_o[4096][4096], mask(tril, unused), pos(arange, unused)
// Output f32 [2048][4096]
// R9: GEMM geometry -> 128x128, BK=64, 4 waves, 64 KiB LDS, 2 blocks/CU co-resident
//     (m97 residency + swizzle + stage-early dbuf). Perfect-fill grids 768/512. attn/prep = r8.

#define DEV __device__ __forceinline__

typedef __attribute__((ext_vector_type(4))) float  f32x4;
typedef __attribute__((ext_vector_type(4))) short  short4v;
typedef __attribute__((ext_vector_type(8))) short  short8;
typedef __attribute__((ext_vector_type(8))) __bf16 bf16x8;

DEV short f32_to_bf16(float x) {
  union { float f; uint32_t u; } v; v.f = x;
  uint32_t r = v.u + 0x7fffu + ((v.u >> 16) & 1u);   // RNE
  return (short)(r >> 16);
}

union frag_u { short4v h[2]; bf16x8 v; short s[8]; };
DEV bf16x8 comb(short4v lo, short4v hi) { frag_u u; u.h[0] = lo; u.h[1] = hi; return u.v; }

DEV f32x4 MFMA(bf16x8 a, bf16x8 b, f32x4 c) {
  return __builtin_amdgcn_mfma_f32_16x16x32_bf16(a, b, c, 0, 0, 0);
}

typedef __attribute__((address_space(1))) void* gas1p;
typedef __attribute__((address_space(3))) void* as3p;
DEV void gld16(const void* g, void* l) {
  __builtin_amdgcn_global_load_lds((gas1p)g, (as3p)l, 16, 0, 0);
}

// ---------------- prep kernels ----------------

__global__ __launch_bounds__(256) void k_cvt_bf16(const float* __restrict__ x,
                                                  short* __restrict__ y, int n4) {
  int i = blockIdx.x * 256 + threadIdx.x;
  int stride = gridDim.x * 256;
  for (; i < n4; i += stride) {
    f32x4 v = ((const f32x4*)x)[i];
    short4v o;
    o[0] = f32_to_bf16(v[0]); o[1] = f32_to_bf16(v[1]);
    o[2] = f32_to_bf16(v[2]); o[3] = f32_to_bf16(v[3]);
    ((short4v*)y)[i] = o;
  }
}

// dst[c][r] = bf16(src[r][c]);  src is [R][C] f32
__global__ __launch_bounds__(256) void k_transpose_bf16(const float* __restrict__ src,
                                                        short* __restrict__ dst, int R, int C) {
  __shared__ float tile[32][33];
  const int c0 = blockIdx.x * 32, r0 = blockIdx.y * 32;
  const int tx = threadIdx.x & 31, ty = threadIdx.x >> 5;
  #pragma unroll
  for (int i = ty; i < 32; i += 8) tile[i][tx] = src[(long)(r0 + i) * C + c0 + tx];
  __syncthreads();
  #pragma unroll
  for (int i = ty; i < 32; i += 8) dst[(long)(c0 + i) * R + r0 + tx] = f32_to_bf16(tile[tx][i]);
}

__global__ void k_rope_tab(float* __restrict__ ct, float* __restrict__ st) {
  const int s = blockIdx.x, j = threadIdx.x;   // grid 2048 x 64
  float inv = powf(10000.0f, -(float)j * (1.0f / 64.0f));
  float a = (float)s * inv;
  ct[s * 64 + j] = cosf(a);
  st[s * 64 + j] = sinf(a);
}

// From C1[s][6144] f32: rope+pack Q->Qh[32][2048][128], K->Kh[8][2048][128], V->Vt[8][128][2048]
__global__ __launch_bounds__(256) void k_rope_pack(const float* __restrict__ C1,
                                                   const float* __restrict__ ct,
                                                   const float* __restrict__ st,
                                                   short* __restrict__ Qh,
                                                   short* __restrict__ Kh,
                                                   short* __restrict__ Vt) {
  const int s = blockIdx.x, t = threadIdx.x;
  const float* row = C1 + (long)s * 6144;
  const float* cr = ct + s * 64;
  const float* sr = st + s * 64;
  for (int i = t; i < 2048; i += 256) {       // Q
    int hh = i >> 6, j = i & 63;
    float c = cr[j], sn = sr[j];
    float x0 = row[hh * 128 + j], x1 = row[hh * 128 + j + 64];
    long o = ((long)hh * 2048 + s) * 128 + j;
    Qh[o]      = f32_to_bf16(x0 * c - x1 * sn);
    Qh[o + 64] = f32_to_bf16(x1 * c + x0 * sn);
  }
  for (int i = t; i < 512; i += 256) {        // K
    int hh = i >> 6, j = i & 63;
    float c = cr[j], sn = sr[j];
    float x0 = row[4096 + hh * 128 + j], x1 = row[4096 + hh * 128 + j + 64];
    long o = ((long)hh * 2048 + s) * 128 + j;
    Kh[o]      = f32_to_bf16(x0 * c - x1 * sn);
    Kh[o + 64] = f32_to_bf16(x1 * c + x0 * sn);
  }
  for (int i = t; i < 1024; i += 256) {       // V transpose
    int hh = i >> 7, d = i & 127;
    Vt[((long)hh * 128 + d) * 2048 + s] = f32_to_bf16(row[5120 + i]);
  }
}

// ---------------- GEMM: C[M][N] = A[M][K] * B^T  (Bt is [N][K] bf16) ----------------
// 128x128 tile, BK=64, 4 waves (2Mx2N). LDS 64 KiB (2 K-tile dbuf) -> 2 blocks/CU resident.
// XOR-swizzled slots (0 conflicts proven), stage-early gld16, compiler-scheduled interleave.

template<int OUT_BF16>
__global__ __launch_bounds__(256, 2) void k_gemm128(const short* __restrict__ A,
                                                    const short* __restrict__ Bt,
                                                    void* __restrict__ Cp,
                                                    int M, int N, int K) {
  __shared__ short As[2][128][64];
  __shared__ short Bs[2][128][64];
  const int tid = threadIdx.x;
  const int lane = tid & 63;
  const int w = tid >> 6;              // 0..3
  const int wr = (w >> 1) * 64;        // wave M-offset
  const int wc = (w & 1) * 64;         // wave N-offset
  const int g = lane >> 4, r16 = lane & 15;
  const long m0 = (long)blockIdx.y * 128;
  const long n0 = (long)blockIdx.x * 128;
  const int l8 = lane >> 3, l7 = lane & 7;
  const int sslot = l7 ^ l8;           // pre-swizzled global source slot (LDS dest stays linear)

  f32x4 acc[4][4] = {};
  const int NT = K >> 6;

  auto stageTile = [&](int kt, int buf) {
    #pragma unroll
    for (int L = 0; L < 4; ++L) {
      const int rb = (w * 4 + L) * 8;        // rows w*32 .. w*32+31
      gld16(A  + (m0 + rb + l8) * (long)K + kt * 64 + sslot * 8, (char*)&As[buf][rb][0]);
      gld16(Bt + (n0 + rb + l8) * (long)K + kt * 64 + sslot * 8, (char*)&Bs[buf][rb][0]);
    }
  };
  // LDS[row][slot] holds global[row][slot ^ (row&7)]
  auto ldA = [&](int m, int kk, int buf) -> bf16x8 {
    const int row = wr + m * 16 + r16;
    const int slot = ((kk << 2) | g) ^ (r16 & 7);
    return *(const bf16x8*)((const char*)&As[buf][0][0] + row * 128 + slot * 16);
  };
  auto ldB = [&](int n, int kk, int buf) -> bf16x8 {
    const int row = wc + n * 16 + r16;
    const int slot = ((kk << 2) | g) ^ (r16 & 7);
    return *(const bf16x8*)((const char*)&Bs[buf][0][0] + row * 128 + slot * 16);
  };

  stageTile(0, 0);
  __syncthreads();

  for (int t = 0; t < NT; ++t) {
    const int buf = t & 1;
    if (t + 1 < NT) stageTile(t + 1, buf ^ 1);   // issued early; lands by boundary sync

    bf16x8 a[2][2], b[2][2];
    #pragma unroll
    for (int mh = 0; mh < 2; ++mh) {
      #pragma unroll
      for (int m = 0; m < 2; ++m)
        #pragma unroll
        for (int kk = 0; kk < 2; ++kk) a[m][kk] = ldA(mh * 2 + m, kk, buf);
      #pragma unroll
      for (int nh = 0; nh < 2; ++nh) {
        #pragma unroll
        for (int n = 0; n < 2; ++n)
          #pragma unroll
          for (int kk = 0; kk < 2; ++kk) b[n][kk] = ldB(nh * 2 + n, kk, buf);
        #pragma unroll
        for (int m = 0; m < 2; ++m)
          #pragma unroll
          for (int n = 0; n < 2; ++n)
            #pragma unroll
            for (int kk = 0; kk < 2; ++kk)
              acc[mh * 2 + m][nh * 2 + n] =
                MFMA(a[m][kk], b[n][kk], acc[mh * 2 + m][nh * 2 + n]);
      }
    }
    __syncthreads();   // drains vmcnt (stage t+1 landed) + lgkm; other resident block covers this
  }

  #pragma unroll
  for (int m = 0; m < 4; ++m) {
    #pragma unroll
    for (int n = 0; n < 4; ++n) {
      const long col = n0 + wc + n * 16 + r16;
      #pragma unroll
      for (int j = 0; j < 4; ++j) {
        const long row = m0 + wr + m * 16 + g * 4 + j;   // C/D: col=lane&15, row=(lane>>4)*4+reg
        if (OUT_BF16) ((short*)Cp)[row * N + col] = f32_to_bf16(acc[m][n][j]);
        else          ((float*)Cp)[row * N + col] = acc[m][n][j];
      }
    }
  }
}

// ---------------- flash attention (causal, GQA 4:1), swapped-QK^T (r5/r8, proven) ----------------

__global__ __launch_bounds__(256) void k_attn(const short* __restrict__ Qh,
                                              const short* __restrict__ Kh,
                                              const short* __restrict__ Vt,
                                              short* __restrict__ O) {
  __shared__ short Kl[64][136];
  __shared__ short Vl[128][72];
  const int h = blockIdx.x, qt = blockIdx.y, hk = h >> 2;
  const int tid = threadIdx.x, lane = tid & 63, w = tid >> 6;
  const int g = lane >> 4, r16 = lane & 15;
  const int q0 = qt * 64 + w * 16;
  const int q_glob = q0 + r16;

  bf16x8 qf[4];
  {
    const short* qb = Qh + ((long)h * 2048 + q0 + r16) * 128;
    #pragma unroll
    for (int c = 0; c < 4; ++c) {
      short4v lo = *(const short4v*)(qb + 32 * c + 4 * g);
      short4v hi = *(const short4v*)(qb + 32 * c + 16 + 4 * g);
      qf[c] = comb(lo, hi);
    }
  }
  const short* Kg = Kh + (long)hk * (2048 * 128);
  const short* Vg = Vt + (long)hk * (128 * 2048);

  f32x4 accO[8] = {};
  float mrun = -1e30f, lrun = 0.0f;

  short8 kpre[4], vpre[4];
  #pragma unroll
  for (int j = 0; j < 4; ++j) {
    const int n = tid + j * 256;
    kpre[j] = *(const short8*)(Kg + ((long)(n >> 4)) * 128 + (n & 15) * 8);
    vpre[j] = *(const short8*)(Vg + (long)(n >> 3) * 2048 + (n & 7) * 8);
  }

  for (int kt = 0; kt <= qt; ++kt) {
    #pragma unroll
    for (int j = 0; j < 4; ++j) {
      const int n = tid + j * 256;
      *(short8*)(&Kl[n >> 4][(n & 15) * 8]) = kpre[j];
      *(short8*)(&Vl[n >> 3][(n & 7) * 8]) = vpre[j];
    }
    __syncthreads();

    if (kt < qt) {
      const long koff = (long)(kt + 1) * 64;
      #pragma unroll
      for (int j = 0; j < 4; ++j) {
        const int n = tid + j * 256;
        kpre[j] = *(const short8*)(Kg + (koff + (n >> 4)) * 128 + (n & 15) * 8);
        vpre[j] = *(const short8*)(Vg + (long)(n >> 3) * 2048 + koff + (n & 7) * 8);
      }
    }

    f32x4 accS[4] = {};
    __builtin_amdgcn_s_setprio(1);
    #pragma unroll
    for (int kvf = 0; kvf < 4; ++kvf) {
      const short* kr = &Kl[kvf * 16 + r16][0];
      #pragma unroll
      for (int c = 0; c < 4; ++c) {
        short4v lo = *(const short4v*)(kr + 32 * c + 4 * g);
        short4v hi = *(const short4v*)(kr + 32 * c + 16 + 4 * g);
        accS[kvf] = MFMA(comb(lo, hi), qf[c], accS[kvf]);
      }
    }
    __builtin_amdgcn_s_setprio(0);

    float sc[4][4];
    float mt = -1e30f;
    #pragma unroll
    for (int kvf = 0; kvf < 4; ++kvf)
      #pragma unroll
      for (int r = 0; r < 4; ++r) {
        float s = accS[kvf][r] * 0.08838834764831845f;
        const int kvg = kt * 64 + kvf * 16 + g * 4 + r;
        if (kvg > q_glob) s = -1e30f;
        sc[kvf][r] = s;
        mt = fmaxf(mt, s);
      }
    mt = fmaxf(mt, __shfl_xor(mt, 16));
    mt = fmaxf(mt, __shfl_xor(mt, 32));
    const float mnew = fmaxf(mrun, mt);
    const float scale = __expf(mrun - mnew);
    float ps = 0.0f;
    #pragma unroll
    for (int kvf = 0; kvf < 4; ++kvf)
      #pragma unroll
      for (int r = 0; r < 4; ++r) {
        float p = __expf(sc[kvf][r] - mnew);
        sc[kvf][r] = p;
        ps += p;
      }
    ps += __shfl_xor(ps, 16);
    ps += __shfl_xor(ps, 32);
    lrun = lrun * scale + ps;
    mrun = mnew;

    frag_u p0, p1;
    #pragma unroll
    for (int e = 0; e < 4; ++e) {
      p0.s[e]     = f32_to_bf16(sc[0][e]);
      p0.s[e + 4] = f32_to_bf16(sc[1][e]);
      p1.s[e]     = f32_to_bf16(sc[2][e]);
      p1.s[e + 4] = f32_to_bf16(sc[3][e]);
    }
    #pragma unroll
    for (int df = 0; df < 8; ++df)
      #pragma unroll
      for (int j = 0; j < 4; ++j) accO[df][j] *= scale;

    __builtin_amdgcn_s_setprio(1);
    #pragma unroll
    for (int df = 0; df < 8; ++df) {
      const short* vr = &Vl[df * 16 + r16][0];
      short4v a0 = *(const short4v*)(vr + 4 * g);
      short4v a1 = *(const short4v*)(vr + 16 + 4 * g);
      short4v a2 = *(const short4v*)(vr + 32 + 4 * g);
      short4v a3 = *(const short4v*)(vr + 48 + 4 * g);
      accO[df] = MFMA(comb(a0, a1), p0.v, accO[df]);
      accO[df] = MFMA(comb(a2, a3), p1.v, accO[df]);
    }
    __builtin_amdgcn_s_setprio(0);
    __syncthreads();
  }

  const float invl = 1.0f / lrun;
  #pragma unroll
  for (int df = 0; df < 8; ++df)
    #pragma unroll
    for (int j = 0; j < 4; ++j) {
      const int d = df * 16 + g * 4 + j;
      O[(long)q_glob * 4096 + h * 128 + d] = f32_to_bf16(accO[df][j] * invl);
    }
}

// ---------------- launch ----------------

extern "C" void kernel_launch(void* const* d_in, const int* in_sizes, int n_in,
                              void* d_out, int out_size, void* d_ws, size_t ws_size,
                              hipStream_t stream) {
  const float* hs   = (const float*)d_in[0];
  const float* wqkv = (const float*)d_in[1];
  const float* wo   = (const float*)d_in[2];

  const size_t OFF_HSB = 0;                 // 16,777,216  (aliased by Qh later)
  const size_t OFF_W1T = 16777216;          // 50,331,648
  const size_t OFF_WOT = 67108864;          // 33,554,432
  const size_t OFF_C1  = 100663296;         // 50,331,648  (first 16.7MB aliased by attn-out)
  const size_t OFF_CT  = 150994944;         //    524,288
  const size_t OFF_ST  = 151519232;         //    524,288
  const size_t OFF_KH  = 152043520;         //  4,194,304
  const size_t OFF_VT  = 156237824;         //  4,194,304  -> end 160,432,128
  if (ws_size < 160432128u) return;

  char* ws = (char*)d_ws;
  short* hsb = (short*)(ws + OFF_HSB);
  short* W1T = (short*)(ws + OFF_W1T);
  short* WoT = (short*)(ws + OFF_WOT);
  float* C1  = (float*)(ws + OFF_C1);
  float* ct  = (float*)(ws + OFF_CT);
  float* st  = (float*)(ws + OFF_ST);
  short* Kh  = (short*)(ws + OFF_KH);
  short* Vt  = (short*)(ws + OFF_VT);
  short* Qh  = hsb;                     // reuse: hsb dead after gemm1
  short* AO  = (short*)(ws + OFF_C1);   // reuse: C1 dead after rope_pack

  k_cvt_bf16<<<2048, 256, 0, stream>>>(hs, hsb, 2048 * 4096 / 4);
  k_transpose_bf16<<<dim3(6144 / 32, 4096 / 32), 256, 0, stream>>>(wqkv, W1T, 4096, 6144);
  k_transpose_bf16<<<dim3(4096 / 32, 4096 / 32), 256, 0, stream>>>(wo, WoT, 4096, 4096);
  k_rope_tab<<<2048, 64, 0, stream>>>(ct, st);
  k_gemm128<0><<<dim3(48, 16), 256, 0, stream>>>(hsb, W1T, (void*)C1, 2048, 6144, 4096);
  k_rope_pack<<<2048, 256, 0, stream>>>(C1, ct, st, Qh, Kh, Vt);
  k_attn<<<dim3(32, 32), 256, 0, stream>>>(Qh, Kh, Vt, AO);   // x=h, y=qt
  k_gemm128<0><<<dim3(32, 16), 256, 0, stream>>>(AO, WoT, (void*)d_out, 2048, 4096, 4096);
}